// Round 4
// baseline (130.844 us; speedup 1.0000x reference)
//
#include <hip/hip_runtime.h>
#include <hip/hip_bf16.h>

#define NB 8
#define NT 2048
#define NC 1024
#define NH 64

typedef __attribute__((ext_vector_type(8))) short bf16x8;
typedef __attribute__((ext_vector_type(4))) short bf16x4;
typedef __attribute__((ext_vector_type(4))) float f32x4;

__device__ __forceinline__ unsigned short f2bf(float f) {
  __hip_bfloat16 h = __float2bfloat16(f);
  return __builtin_bit_cast(unsigned short, h);
}

__device__ __forceinline__ f32x4 mfma32(bf16x8 a, bf16x8 b, f32x4 c) {
  return __builtin_amdgcn_mfma_f32_16x16x32_bf16(a, b, c, 0, 0, 0);
}

#if __has_builtin(__builtin_amdgcn_mfma_f32_16x16x16bf16_1k)
__device__ __forceinline__ f32x4 mfma16(bf16x4 a, bf16x4 b, f32x4 c) {
  return __builtin_amdgcn_mfma_f32_16x16x16bf16_1k(a, b, c, 0, 0, 0);
}
#else
__device__ __forceinline__ f32x4 mfma16(bf16x4 a, bf16x4 b, f32x4 c) {
  asm volatile("v_mfma_f32_16x16x16_bf16 %0, %1, %2, %0\n\ts_nop 7"
               : "+v"(c) : "v"(a), "v"(b));
  return c;
}
#endif

// ---------------------------------------------------------------------------
// Kernel 0: weight transpose+convert. W[1024][64] f32 -> Wt[64][1024] bf16.
// Folds softmax scale * log2(e) into Wq so attention can use exp2 directly.
// ---------------------------------------------------------------------------
__global__ __launch_bounds__(256) void wt_kernel(const float* __restrict__ Wq,
                                                 const float* __restrict__ Wk,
                                                 const float* __restrict__ Wv,
                                                 unsigned short* __restrict__ Wt) {
  __shared__ float lds[64][65];
  int wi = blockIdx.x >> 4, kt = blockIdx.x & 15;
  const float* W = (wi == 0) ? Wq : ((wi == 1) ? Wk : Wv);
  float scale = (wi == 0) ? 0.18033688011112043f : 1.0f;  // 0.125 * log2(e)
  int tid = threadIdx.x;
#pragma unroll
  for (int i = 0; i < 16; ++i) {
    int idx = tid + i * 256;
    lds[idx >> 6][idx & 63] = W[(size_t)(kt * 64 + (idx >> 6)) * NH + (idx & 63)] * scale;
  }
  __syncthreads();
#pragma unroll
  for (int i = 0; i < 16; ++i) {
    int idx = tid + i * 256;
    int n = idx >> 6, kk = idx & 63;
    Wt[(size_t)(wi * 64 + n) * NC + kt * 64 + kk] = f2bf(lds[kk][n]);
  }
}

// ---------------------------------------------------------------------------
// Kernel 1: fused QKV projection, v4.
// 512 blocks x 256 thr (4 waves). Block = 32 rows. Wave w owns col-slice
// w*16 of q,k,v (no redundant weight streams): per K-step 2 ds_read_b128 +
// 3 x 16B weight loads + 6 MFMA. NEW: 4-phase pipeline (K=256 per phase,
// double-buffered 2x16KB LDS): phase p+1's HBM loads issue before the
// barrier, compute(p) hides them, converted write lands after. One barrier
// per phase.
// ---------------------------------------------------------------------------
__global__ __launch_bounds__(256) void proj_kernel(const float* __restrict__ x,
                                                   const unsigned short* __restrict__ Wt,
                                                   unsigned short* __restrict__ qo,
                                                   unsigned short* __restrict__ ko,
                                                   unsigned short* __restrict__ vo) {
  __shared__ __align__(16) unsigned short xs[2][32 * 256];  // 2 x 16KB, swizzled
  __shared__ __align__(16) unsigned short vlds[64][40];

  int tid = threadIdx.x;
  int lane = tid & 63, w = tid >> 6;
  int ln = lane & 15, g = lane >> 4;
  int row0 = blockIdx.x * 32;

  int nc = w * 16 + ln;
  const unsigned short* wpq = Wt + (size_t)(0 * 64 + nc) * NC + g * 8;
  const unsigned short* wpk = Wt + (size_t)(1 * 64 + nc) * NC + g * 8;
  const unsigned short* wpv = Wt + (size_t)(2 * 64 + nc) * NC + g * 8;

  // staging mapping: thread -> (row = tid>>3, si = tid&7); 8 float4 per phase
  int srow = tid >> 3, si = tid & 7;
  const float* xbase = x + (size_t)(row0 + srow) * NC + si * 4;

  f32x4 acc[2][3];
#pragma unroll
  for (int rf = 0; rf < 2; ++rf)
#pragma unroll
    for (int j = 0; j < 3; ++j) acc[rf][j] = (f32x4){0.f, 0.f, 0.f, 0.f};

  float4 R[8];
  // ---- prologue: load + write phase 0
#pragma unroll
  for (int j = 0; j < 8; ++j) R[j] = *(const float4*)(xbase + j * 32);
#pragma unroll
  for (int j = 0; j < 8; ++j) {
    bf16x4 b4;
    b4[0] = (short)f2bf(R[j].x); b4[1] = (short)f2bf(R[j].y);
    b4[2] = (short)f2bf(R[j].z); b4[3] = (short)f2bf(R[j].w);
    int byte = (srow * 512 + si * 8 + j * 64) ^ ((srow & 7) << 4);
    *(bf16x4*)((char*)xs[0] + byte) = b4;
  }

#pragma unroll 1
  for (int p = 0; p < 4; ++p) {
    // issue next phase's HBM loads (hidden under compute below)
    if (p < 3) {
#pragma unroll
      for (int j = 0; j < 8; ++j)
        R[j] = *(const float4*)(xbase + (p + 1) * 256 + j * 32);
    }
    __syncthreads();
    // compute phase p from buf[p&1]
    const char* bufc = (const char*)xs[p & 1];
#pragma unroll
    for (int c0 = 0; c0 < 256; c0 += 32) {
      int b0 = (ln * 512 + (c0 + g * 8) * 2) ^ ((ln & 7) << 4);
      int b1 = ((16 + ln) * 512 + (c0 + g * 8) * 2) ^ ((ln & 7) << 4);
      bf16x8 a0 = *(const bf16x8*)(bufc + b0);
      bf16x8 a1 = *(const bf16x8*)(bufc + b1);
      int kg = p * 256 + c0;
      bf16x8 bq = *(const bf16x8*)(wpq + kg);
      bf16x8 bk = *(const bf16x8*)(wpk + kg);
      bf16x8 bv = *(const bf16x8*)(wpv + kg);
      acc[0][0] = mfma32(a0, bq, acc[0][0]);
      acc[1][0] = mfma32(a1, bq, acc[1][0]);
      acc[0][1] = mfma32(a0, bk, acc[0][1]);
      acc[1][1] = mfma32(a1, bk, acc[1][1]);
      acc[0][2] = mfma32(a0, bv, acc[0][2]);
      acc[1][2] = mfma32(a1, bv, acc[1][2]);
    }
    // write phase p+1 into the other buffer (readers of it passed the barrier)
    if (p < 3) {
      char* bufw = (char*)xs[(p + 1) & 1];
#pragma unroll
      for (int j = 0; j < 8; ++j) {
        bf16x4 b4;
        b4[0] = (short)f2bf(R[j].x); b4[1] = (short)f2bf(R[j].y);
        b4[2] = (short)f2bf(R[j].z); b4[3] = (short)f2bf(R[j].w);
        int byte = (srow * 512 + si * 8 + j * 64) ^ ((srow & 7) << 4);
        *(bf16x4*)(bufw + byte) = b4;
      }
    }
  }

  // ---- epilogue: q,k direct; v via LDS transpose
#pragma unroll
  for (int rf = 0; rf < 2; ++rf)
#pragma unroll
    for (int r = 0; r < 4; ++r) {
      int row = row0 + rf * 16 + g * 4 + r;
      qo[(size_t)row * NH + nc] = f2bf(acc[rf][0][r]);
      ko[(size_t)row * NH + nc] = f2bf(acc[rf][1][r]);
      vlds[nc][rf * 16 + g * 4 + r] = f2bf(acc[rf][2][r]);
    }
  __syncthreads();
  {
    int b = row0 / NT, t0b = row0 % NT;
    int hh = tid >> 2, ts = (tid & 3) * 8;
    *(bf16x8*)(vo + (size_t)(b * NH + hh) * NT + t0b + ts) = *(const bf16x8*)&vlds[hh][ts];
  }
}

// ---------------------------------------------------------------------------
// Kernel 2: causal flash attention, v4. Swapped QK^T (S^T = mfma(K,Q)) chains
// into PV's B-operand with zero shuffles. 4-way key-split across waves with
// private online-softmax state folded by wave 0. NEW: adjacent-pair causal
// balance swizzle (bid even/odd -> tiles j / 127-j) + s_setprio around MFMA.
// 1024 blocks x 256 thr.
// ---------------------------------------------------------------------------
__global__ __launch_bounds__(256) void attn_kernel(const unsigned short* __restrict__ qw,
                                                   const unsigned short* __restrict__ kw,
                                                   const unsigned short* __restrict__ vw,
                                                   float* __restrict__ out) {
  int tid = threadIdx.x;
  int lane = tid & 63, ks = tid >> 6;
  int ln = lane & 15, g = lane >> 4;
  int bid = blockIdx.x;
  int pair = bid >> 1;
  int b = pair >> 6, jj = pair & 63;
  int qtile = (bid & 1) ? (127 - jj) : jj;  // adjacent blocks complementary
  int t0 = qtile * 16;
  int tq = t0 + ln;

  const unsigned short* qp = qw + (size_t)(b * NT + tq) * NH + g * 8;
  bf16x8 qf0 = *(const bf16x8*)(qp);
  bf16x8 qf1 = *(const bf16x8*)(qp + 32);

  const unsigned short* kb = kw + (size_t)b * NT * NH + g * 8;
  const unsigned short* vb = vw + (size_t)b * NH * NT;

  f32x4 oacc[4];
#pragma unroll
  for (int i = 0; i < 4; ++i) oacc[i] = (f32x4){0.f, 0.f, 0.f, 0.f};
  float m = -1e30f, lsum = 0.f;

  int send = t0 + 16;                          // exclusive key bound
  for (int s0 = ks * 64; s0 < send; s0 += 256) {
    // ---- S^T = K_tile x Q^T
    f32x4 st4[4];
#pragma unroll
    for (int st = 0; st < 4; ++st) {
      const unsigned short* kp = kb + (size_t)(s0 + st * 16 + ln) * NH;
      bf16x8 k0 = *(const bf16x8*)(kp);
      bf16x8 k1 = *(const bf16x8*)(kp + 32);
      f32x4 a = (f32x4){0.f, 0.f, 0.f, 0.f};
      __builtin_amdgcn_s_setprio(1);
      a = mfma32(k0, qf0, a);
      a = mfma32(k1, qf1, a);
      __builtin_amdgcn_s_setprio(0);
      st4[st] = a;
    }
    // ---- causal mask (wave-uniform branch)
    if (s0 + 63 > t0) {
#pragma unroll
      for (int st = 0; st < 4; ++st)
#pragma unroll
        for (int r = 0; r < 4; ++r)
          if (s0 + st * 16 + g * 4 + r > tq) st4[st][r] = -1e30f;
    }
    // ---- online softmax (base-2 logits) with deferred rescale
    float tmax = -1e30f;
#pragma unroll
    for (int st = 0; st < 4; ++st)
#pragma unroll
      for (int r = 0; r < 4; ++r) tmax = fmaxf(tmax, st4[st][r]);
    tmax = fmaxf(tmax, __shfl_xor(tmax, 16));
    tmax = fmaxf(tmax, __shfl_xor(tmax, 32));
    if (__any(tmax > m + 8.f)) {
      float mnew = fmaxf(m, tmax);
      float sfac = exp2f(m - mnew);
      lsum *= sfac;
#pragma unroll
      for (int hf = 0; hf < 4; ++hf)
#pragma unroll
        for (int r = 0; r < 4; ++r) oacc[hf][r] *= sfac;
      m = mnew;
    }

    float psum = 0.f;
    bf16x4 pb[4];
#pragma unroll
    for (int st = 0; st < 4; ++st) {
#pragma unroll
      for (int r = 0; r < 4; ++r) {
        float p = exp2f(st4[st][r] - m);
        psum += p;
        pb[st][r] = (short)f2bf(p);
      }
    }
    psum += __shfl_xor(psum, 16);
    psum += __shfl_xor(psum, 32);
    lsum += psum;

    // ---- PV: out^T[h][t] += vT x P^T
    __builtin_amdgcn_s_setprio(1);
#pragma unroll
    for (int hf = 0; hf < 4; ++hf) {
      const unsigned short* vp = vb + (size_t)(hf * 16 + ln) * NT + s0 + g * 4;
#pragma unroll
      for (int st = 0; st < 4; ++st) {
        bf16x4 va = *(const bf16x4*)(vp + st * 16);
        oacc[hf] = mfma16(va, pb[st], oacc[hf]);
      }
    }
    __builtin_amdgcn_s_setprio(0);
  }

  // ---- fold the 4 key-split partials (wave 0 accumulates)
  __shared__ float mbuf[3][64][20];
  __shared__ float olds[16][68];
  if (ks) {
    float* d = mbuf[ks - 1][lane];
    d[0] = m; d[1] = lsum;
#pragma unroll
    for (int hf = 0; hf < 4; ++hf)
#pragma unroll
      for (int r = 0; r < 4; ++r) d[2 + hf * 4 + r] = oacc[hf][r];
  }
  __syncthreads();
  if (ks == 0) {
#pragma unroll
    for (int j = 0; j < 3; ++j) {
      const float* d = mbuf[j][lane];
      float mB = d[0], lB = d[1];
      float mx = fmaxf(m, mB);
      float fA = exp2f(m - mx), fB = exp2f(mB - mx);
      lsum = lsum * fA + lB * fB;
#pragma unroll
      for (int hf = 0; hf < 4; ++hf)
#pragma unroll
        for (int r = 0; r < 4; ++r)
          oacc[hf][r] = oacc[hf][r] * fA + d[2 + hf * 4 + r] * fB;
      m = mx;
    }
    float inv = 1.f / lsum;
#pragma unroll
    for (int hf = 0; hf < 4; ++hf)
#pragma unroll
      for (int r = 0; r < 4; ++r)
        olds[ln][hf * 16 + g * 4 + r] = oacc[hf][r] * inv;
  }
  __syncthreads();
  // ---- transposed store out[b][t][h]
  if (tid < 64) {
    int tl = tid >> 2, h0 = (tid & 3) * 16;
    size_t obase = (size_t)(b * NT + t0 + tl) * NH + h0;
#pragma unroll
    for (int vv = 0; vv < 4; ++vv) {
      float4 t4 = make_float4(olds[tl][h0 + vv * 4 + 0], olds[tl][h0 + vv * 4 + 1],
                              olds[tl][h0 + vv * 4 + 2], olds[tl][h0 + vv * 4 + 3]);
      *(float4*)(out + obase + vv * 4) = t4;
    }
  }
}

// ---------------------------------------------------------------------------
extern "C" void kernel_launch(void* const* d_in, const int* in_sizes, int n_in,
                              void* d_out, int out_size, void* d_ws, size_t ws_size,
                              hipStream_t stream) {
  const float* x  = (const float*)d_in[0];
  const float* Wq = (const float*)d_in[1];
  const float* Wk = (const float*)d_in[2];
  const float* Wv = (const float*)d_in[3];
  float* out = (float*)d_out;

  unsigned short* Wt = (unsigned short*)d_ws;
  unsigned short* q  = (unsigned short*)((char*)d_ws + (1 << 19));
  unsigned short* k  = q + (size_t)NB * NT * NH;
  unsigned short* v  = k + (size_t)NB * NT * NH;

  wt_kernel<<<48, 256, 0, stream>>>(Wq, Wk, Wv, Wt);
  proj_kernel<<<(NB * NT) / 32, 256, 0, stream>>>(x, Wt, q, k, v);
  attn_kernel<<<1024, 256, 0, stream>>>(q, k, v, out);
}

// Round 5
// 90.360 us; speedup vs baseline: 1.4480x; 1.4480x over previous
//
#include <hip/hip_runtime.h>
#include <hip/hip_bf16.h>

#define NB 8
#define NT 2048
#define NC 1024
#define NH 64

typedef __attribute__((ext_vector_type(8))) short bf16x8;
typedef __attribute__((ext_vector_type(4))) short bf16x4;
typedef __attribute__((ext_vector_type(4))) float f32x4;

__device__ __forceinline__ unsigned short f2bf(float f) {
  __hip_bfloat16 h = __float2bfloat16(f);
  return __builtin_bit_cast(unsigned short, h);
}

__device__ __forceinline__ f32x4 mfma32(bf16x8 a, bf16x8 b, f32x4 c) {
  return __builtin_amdgcn_mfma_f32_16x16x32_bf16(a, b, c, 0, 0, 0);
}

#if __has_builtin(__builtin_amdgcn_mfma_f32_16x16x16bf16_1k)
__device__ __forceinline__ f32x4 mfma16(bf16x4 a, bf16x4 b, f32x4 c) {
  return __builtin_amdgcn_mfma_f32_16x16x16bf16_1k(a, b, c, 0, 0, 0);
}
#else
__device__ __forceinline__ f32x4 mfma16(bf16x4 a, bf16x4 b, f32x4 c) {
  asm volatile("v_mfma_f32_16x16x16_bf16 %0, %1, %2, %0\n\ts_nop 7"
               : "+v"(c) : "v"(a), "v"(b));
  return c;
}
#endif

// ---------------------------------------------------------------------------
// Kernel 0: weight transpose+convert. W[1024][64] f32 -> Wt[64][1024] bf16.
// Folds softmax scale * log2(e) into Wq so attention can use exp2 directly.
// ---------------------------------------------------------------------------
__global__ __launch_bounds__(256) void wt_kernel(const float* __restrict__ Wq,
                                                 const float* __restrict__ Wk,
                                                 const float* __restrict__ Wv,
                                                 unsigned short* __restrict__ Wt) {
  __shared__ float lds[64][65];
  int wi = blockIdx.x >> 4, kt = blockIdx.x & 15;
  const float* W = (wi == 0) ? Wq : ((wi == 1) ? Wk : Wv);
  float scale = (wi == 0) ? 0.18033688011112043f : 1.0f;  // 0.125 * log2(e)
  int tid = threadIdx.x;
#pragma unroll
  for (int i = 0; i < 16; ++i) {
    int idx = tid + i * 256;
    lds[idx >> 6][idx & 63] = W[(size_t)(kt * 64 + (idx >> 6)) * NH + (idx & 63)] * scale;
  }
  __syncthreads();
#pragma unroll
  for (int i = 0; i < 16; ++i) {
    int idx = tid + i * 256;
    int n = idx >> 6, kk = idx & 63;
    Wt[(size_t)(wi * 64 + n) * NC + kt * 64 + kk] = f2bf(lds[kk][n]);
  }
}

// ---------------------------------------------------------------------------
// Kernel 1: fused QKV projection, v4.1.
// 512 blocks x 256 thr (4 waves). Block = 32 rows. Wave w owns col-slice
// w*16 of q,k,v: per K-step 2 ds_read_b128 + 3 x 16B weight loads + 6 MFMA.
// 4-phase double-buffered pipeline; NEW ORDER: barrier -> issue loads(p+1)
// -> compute(p) -> write(p+1). (Issuing before the barrier was useless: the
// compiler drains vmcnt(0) at every __syncthreads, serializing the phase.)
// ---------------------------------------------------------------------------
__global__ __launch_bounds__(256) void proj_kernel(const float* __restrict__ x,
                                                   const unsigned short* __restrict__ Wt,
                                                   unsigned short* __restrict__ qo,
                                                   unsigned short* __restrict__ ko,
                                                   unsigned short* __restrict__ vo) {
  __shared__ __align__(16) unsigned short xs[2][32 * 256];  // 2 x 16KB, swizzled
  __shared__ __align__(16) unsigned short vlds[64][40];

  int tid = threadIdx.x;
  int lane = tid & 63, w = tid >> 6;
  int ln = lane & 15, g = lane >> 4;
  int row0 = blockIdx.x * 32;

  int nc = w * 16 + ln;
  const unsigned short* wpq = Wt + (size_t)(0 * 64 + nc) * NC + g * 8;
  const unsigned short* wpk = Wt + (size_t)(1 * 64 + nc) * NC + g * 8;
  const unsigned short* wpv = Wt + (size_t)(2 * 64 + nc) * NC + g * 8;

  // staging mapping: thread -> (row = tid>>3, si = tid&7); 8 float4 per phase
  int srow = tid >> 3, si = tid & 7;
  const float* xbase = x + (size_t)(row0 + srow) * NC + si * 4;

  f32x4 acc[2][3];
#pragma unroll
  for (int rf = 0; rf < 2; ++rf)
#pragma unroll
    for (int j = 0; j < 3; ++j) acc[rf][j] = (f32x4){0.f, 0.f, 0.f, 0.f};

  float4 R[8];
  // ---- prologue: load + write phase 0
#pragma unroll
  for (int j = 0; j < 8; ++j) R[j] = *(const float4*)(xbase + j * 32);
#pragma unroll
  for (int j = 0; j < 8; ++j) {
    bf16x4 b4;
    b4[0] = (short)f2bf(R[j].x); b4[1] = (short)f2bf(R[j].y);
    b4[2] = (short)f2bf(R[j].z); b4[3] = (short)f2bf(R[j].w);
    int byte = (srow * 512 + si * 8 + j * 64) ^ ((srow & 7) << 4);
    *(bf16x4*)((char*)xs[0] + byte) = b4;
  }

#pragma unroll 1
  for (int p = 0; p < 4; ++p) {
    __syncthreads();   // buf[p&1] fully written; nothing in flight here
    // issue next phase's HBM loads NOW -> they overlap compute(p)
    if (p < 3) {
#pragma unroll
      for (int j = 0; j < 8; ++j)
        R[j] = *(const float4*)(xbase + (p + 1) * 256 + j * 32);
    }
    // compute phase p from buf[p&1]
    const char* bufc = (const char*)xs[p & 1];
#pragma unroll
    for (int c0 = 0; c0 < 256; c0 += 32) {
      int b0 = (ln * 512 + (c0 + g * 8) * 2) ^ ((ln & 7) << 4);
      int b1 = ((16 + ln) * 512 + (c0 + g * 8) * 2) ^ ((ln & 7) << 4);
      bf16x8 a0 = *(const bf16x8*)(bufc + b0);
      bf16x8 a1 = *(const bf16x8*)(bufc + b1);
      int kg = p * 256 + c0;
      bf16x8 bq = *(const bf16x8*)(wpq + kg);
      bf16x8 bk = *(const bf16x8*)(wpk + kg);
      bf16x8 bv = *(const bf16x8*)(wpv + kg);
      acc[0][0] = mfma32(a0, bq, acc[0][0]);
      acc[1][0] = mfma32(a1, bq, acc[1][0]);
      acc[0][1] = mfma32(a0, bk, acc[0][1]);
      acc[1][1] = mfma32(a1, bk, acc[1][1]);
      acc[0][2] = mfma32(a0, bv, acc[0][2]);
      acc[1][2] = mfma32(a1, bv, acc[1][2]);
    }
    // write phase p+1 into the other buffer (its readers passed the barrier)
    if (p < 3) {
      char* bufw = (char*)xs[(p + 1) & 1];
#pragma unroll
      for (int j = 0; j < 8; ++j) {
        bf16x4 b4;
        b4[0] = (short)f2bf(R[j].x); b4[1] = (short)f2bf(R[j].y);
        b4[2] = (short)f2bf(R[j].z); b4[3] = (short)f2bf(R[j].w);
        int byte = (srow * 512 + si * 8 + j * 64) ^ ((srow & 7) << 4);
        *(bf16x4*)(bufw + byte) = b4;
      }
    }
  }

  // ---- epilogue: q,k direct; v via LDS transpose
#pragma unroll
  for (int rf = 0; rf < 2; ++rf)
#pragma unroll
    for (int r = 0; r < 4; ++r) {
      int row = row0 + rf * 16 + g * 4 + r;
      qo[(size_t)row * NH + nc] = f2bf(acc[rf][0][r]);
      ko[(size_t)row * NH + nc] = f2bf(acc[rf][1][r]);
      vlds[nc][rf * 16 + g * 4 + r] = f2bf(acc[rf][2][r]);
    }
  __syncthreads();
  {
    int b = row0 / NT, t0b = row0 % NT;
    int hh = tid >> 2, ts = (tid & 3) * 8;
    *(bf16x8*)(vo + (size_t)(b * NH + hh) * NT + t0b + ts) = *(const bf16x8*)&vlds[hh][ts];
  }
}

// ---------------------------------------------------------------------------
// Kernel 2: causal flash attention, v5. Swapped QK^T (S^T = mfma(K,Q)) chains
// into PV's B-operand with zero shuffles. 4-way key-split across waves,
// private online-softmax state folded by wave 0, defer-rescale (THR=8).
// NEW: XCD-balanced mapping — b = bid&7 (one batch per XCD under round-robin
// dispatch -> K/V L2-resident), s = bid>>3, qtile = s<64 ? s : 191-s (every
// CU's 4 slots {c,c+32,c+64,c+96} sum to constant work). No setprio.
// 1024 blocks x 256 thr.
// ---------------------------------------------------------------------------
__global__ __launch_bounds__(256) void attn_kernel(const unsigned short* __restrict__ qw,
                                                   const unsigned short* __restrict__ kw,
                                                   const unsigned short* __restrict__ vw,
                                                   float* __restrict__ out) {
  int tid = threadIdx.x;
  int lane = tid & 63, ks = tid >> 6;
  int ln = lane & 15, g = lane >> 4;
  int bid = blockIdx.x;
  int b = bid & 7;
  int s = bid >> 3;
  int qtile = (s < 64) ? s : 191 - s;
  int t0 = qtile * 16;
  int tq = t0 + ln;

  const unsigned short* qp = qw + (size_t)(b * NT + tq) * NH + g * 8;
  bf16x8 qf0 = *(const bf16x8*)(qp);
  bf16x8 qf1 = *(const bf16x8*)(qp + 32);

  const unsigned short* kb = kw + (size_t)b * NT * NH + g * 8;
  const unsigned short* vb = vw + (size_t)b * NH * NT;

  f32x4 oacc[4];
#pragma unroll
  for (int i = 0; i < 4; ++i) oacc[i] = (f32x4){0.f, 0.f, 0.f, 0.f};
  float m = -1e30f, lsum = 0.f;

  int send = t0 + 16;                          // exclusive key bound
  for (int s0 = ks * 64; s0 < send; s0 += 256) {
    // ---- S^T = K_tile x Q^T
    f32x4 st4[4];
#pragma unroll
    for (int st = 0; st < 4; ++st) {
      const unsigned short* kp = kb + (size_t)(s0 + st * 16 + ln) * NH;
      bf16x8 k0 = *(const bf16x8*)(kp);
      bf16x8 k1 = *(const bf16x8*)(kp + 32);
      f32x4 a = (f32x4){0.f, 0.f, 0.f, 0.f};
      a = mfma32(k0, qf0, a);
      a = mfma32(k1, qf1, a);
      st4[st] = a;
    }
    // ---- causal mask (wave-uniform branch)
    if (s0 + 63 > t0) {
#pragma unroll
      for (int st = 0; st < 4; ++st)
#pragma unroll
        for (int r = 0; r < 4; ++r)
          if (s0 + st * 16 + g * 4 + r > tq) st4[st][r] = -1e30f;
    }
    // ---- online softmax (base-2 logits) with deferred rescale
    float tmax = -1e30f;
#pragma unroll
    for (int st = 0; st < 4; ++st)
#pragma unroll
      for (int r = 0; r < 4; ++r) tmax = fmaxf(tmax, st4[st][r]);
    tmax = fmaxf(tmax, __shfl_xor(tmax, 16));
    tmax = fmaxf(tmax, __shfl_xor(tmax, 32));
    if (__any(tmax > m + 8.f)) {
      float mnew = fmaxf(m, tmax);
      float sfac = exp2f(m - mnew);
      lsum *= sfac;
#pragma unroll
      for (int hf = 0; hf < 4; ++hf)
#pragma unroll
        for (int r = 0; r < 4; ++r) oacc[hf][r] *= sfac;
      m = mnew;
    }

    float psum = 0.f;
    bf16x4 pb[4];
#pragma unroll
    for (int st = 0; st < 4; ++st) {
#pragma unroll
      for (int r = 0; r < 4; ++r) {
        float p = exp2f(st4[st][r] - m);
        psum += p;
        pb[st][r] = (short)f2bf(p);
      }
    }
    psum += __shfl_xor(psum, 16);
    psum += __shfl_xor(psum, 32);
    lsum += psum;

    // ---- PV: out^T[h][t] += vT x P^T
#pragma unroll
    for (int hf = 0; hf < 4; ++hf) {
      const unsigned short* vp = vb + (size_t)(hf * 16 + ln) * NT + s0 + g * 4;
#pragma unroll
      for (int st = 0; st < 4; ++st) {
        bf16x4 va = *(const bf16x4*)(vp + st * 16);
        oacc[hf] = mfma16(va, pb[st], oacc[hf]);
      }
    }
  }

  // ---- fold the 4 key-split partials (wave 0 accumulates)
  __shared__ float mbuf[3][64][20];
  __shared__ float olds[16][68];
  if (ks) {
    float* d = mbuf[ks - 1][lane];
    d[0] = m; d[1] = lsum;
#pragma unroll
    for (int hf = 0; hf < 4; ++hf)
#pragma unroll
      for (int r = 0; r < 4; ++r) d[2 + hf * 4 + r] = oacc[hf][r];
  }
  __syncthreads();
  if (ks == 0) {
#pragma unroll
    for (int j = 0; j < 3; ++j) {
      const float* d = mbuf[j][lane];
      float mB = d[0], lB = d[1];
      float mx = fmaxf(m, mB);
      float fA = exp2f(m - mx), fB = exp2f(mB - mx);
      lsum = lsum * fA + lB * fB;
#pragma unroll
      for (int hf = 0; hf < 4; ++hf)
#pragma unroll
        for (int r = 0; r < 4; ++r)
          oacc[hf][r] = oacc[hf][r] * fA + d[2 + hf * 4 + r] * fB;
      m = mx;
    }
    float inv = 1.f / lsum;
#pragma unroll
    for (int hf = 0; hf < 4; ++hf)
#pragma unroll
      for (int r = 0; r < 4; ++r)
        olds[ln][hf * 16 + g * 4 + r] = oacc[hf][r] * inv;
  }
  __syncthreads();
  // ---- transposed store out[b][t][h]
  if (tid < 64) {
    int tl = tid >> 2, h0 = (tid & 3) * 16;
    size_t obase = (size_t)(b * NT + t0 + tl) * NH + h0;
#pragma unroll
    for (int vv = 0; vv < 4; ++vv) {
      float4 t4 = make_float4(olds[tl][h0 + vv * 4 + 0], olds[tl][h0 + vv * 4 + 1],
                              olds[tl][h0 + vv * 4 + 2], olds[tl][h0 + vv * 4 + 3]);
      *(float4*)(out + obase + vv * 4) = t4;
    }
  }
}

// ---------------------------------------------------------------------------
extern "C" void kernel_launch(void* const* d_in, const int* in_sizes, int n_in,
                              void* d_out, int out_size, void* d_ws, size_t ws_size,
                              hipStream_t stream) {
  const float* x  = (const float*)d_in[0];
  const float* Wq = (const float*)d_in[1];
  const float* Wk = (const float*)d_in[2];
  const float* Wv = (const float*)d_in[3];
  float* out = (float*)d_out;

  unsigned short* Wt = (unsigned short*)d_ws;
  unsigned short* q  = (unsigned short*)((char*)d_ws + (1 << 19));
  unsigned short* k  = q + (size_t)NB * NT * NH;
  unsigned short* v  = k + (size_t)NB * NT * NH;

  wt_kernel<<<48, 256, 0, stream>>>(Wq, Wk, Wv, Wt);
  proj_kernel<<<(NB * NT) / 32, 256, 0, stream>>>(x, Wt, q, k, v);
  attn_kernel<<<1024, 256, 0, stream>>>(q, k, v, out);
}

// Round 6
// 77.041 us; speedup vs baseline: 1.6984x; 1.1729x over previous
//
#include <hip/hip_runtime.h>
#include <hip/hip_bf16.h>

#define NB 8
#define NT 2048
#define NC 1024
#define NH 64

typedef __attribute__((ext_vector_type(8))) short bf16x8;
typedef __attribute__((ext_vector_type(4))) short bf16x4;
typedef __attribute__((ext_vector_type(4))) float f32x4;

__device__ __forceinline__ unsigned short f2bf(float f) {
  __hip_bfloat16 h = __float2bfloat16(f);
  return __builtin_bit_cast(unsigned short, h);
}

__device__ __forceinline__ f32x4 mfma32(bf16x8 a, bf16x8 b, f32x4 c) {
  return __builtin_amdgcn_mfma_f32_16x16x32_bf16(a, b, c, 0, 0, 0);
}

#if __has_builtin(__builtin_amdgcn_mfma_f32_16x16x16bf16_1k)
__device__ __forceinline__ f32x4 mfma16(bf16x4 a, bf16x4 b, f32x4 c) {
  return __builtin_amdgcn_mfma_f32_16x16x16bf16_1k(a, b, c, 0, 0, 0);
}
#else
__device__ __forceinline__ f32x4 mfma16(bf16x4 a, bf16x4 b, f32x4 c) {
  asm volatile("v_mfma_f32_16x16x16_bf16 %0, %1, %2, %0\n\ts_nop 7"
               : "+v"(c) : "v"(a), "v"(b));
  return c;
}
#endif

// async global->LDS, 16B per lane, wave-uniform LDS base + lane*16
__device__ __forceinline__ void stage16(const float* src, char* lds_base, int lane) {
#if __has_builtin(__builtin_amdgcn_global_load_lds)
  __builtin_amdgcn_global_load_lds(
      (const __attribute__((address_space(1))) void*)src,
      (__attribute__((address_space(3))) void*)lds_base, 16, 0, 0);
  (void)lane;
#else
  *(f32x4*)(lds_base + lane * 16) = *(const f32x4*)src;
#endif
}

// ---------------------------------------------------------------------------
// Kernel 0: weight transpose+convert. W[1024][64] f32 -> Wt[64][1024] bf16.
// Folds softmax scale * log2(e) into Wq so attention can use exp2 directly.
// ---------------------------------------------------------------------------
__global__ __launch_bounds__(256) void wt_kernel(const float* __restrict__ Wq,
                                                 const float* __restrict__ Wk,
                                                 const float* __restrict__ Wv,
                                                 unsigned short* __restrict__ Wt) {
  __shared__ float lds[64][65];
  int wi = blockIdx.x >> 4, kt = blockIdx.x & 15;
  const float* W = (wi == 0) ? Wq : ((wi == 1) ? Wk : Wv);
  float scale = (wi == 0) ? 0.18033688011112043f : 1.0f;  // 0.125 * log2(e)
  int tid = threadIdx.x;
#pragma unroll
  for (int i = 0; i < 16; ++i) {
    int idx = tid + i * 256;
    lds[idx >> 6][idx & 63] = W[(size_t)(kt * 64 + (idx >> 6)) * NH + (idx & 63)] * scale;
  }
  __syncthreads();
#pragma unroll
  for (int i = 0; i < 16; ++i) {
    int idx = tid + i * 256;
    int n = idx >> 6, kk = idx & 63;
    Wt[(size_t)(wi * 64 + n) * NC + kt * 64 + kk] = f2bf(lds[kk][n]);
  }
}

// ---------------------------------------------------------------------------
// Kernel 1: fused QKV projection, v5 (m97-style).
// 512 blocks x 256 thr (4 waves). Block = 32 rows. x staged as RAW F32 via
// global_load_lds (no VGPR roundtrip), BK=128, 8 phases, double-buffered
// 2x16KB, ONE barrier per phase. Granule-XOR swizzle (colblk ^= row&7, 16B
// granules) applied on the pre-swizzled GLOBAL source (rule #21: LDS dest
// stays linear) and on the ds_read side. f32->bf16 conversion happens at
// A-frag read. Wave w owns output cols [16w,16w+16) of q,k,v: per K-step
// 4 ds_read_b128(f32) + 3 x 16B weight loads + 6 MFMA.
// ---------------------------------------------------------------------------
__global__ __launch_bounds__(256) void proj_kernel(const float* __restrict__ x,
                                                   const unsigned short* __restrict__ Wt,
                                                   unsigned short* __restrict__ qo,
                                                   unsigned short* __restrict__ ko,
                                                   unsigned short* __restrict__ vo) {
  __shared__ __align__(16) char xs2[2][16384];   // 32x128 f32 each, swizzled
  __shared__ __align__(16) unsigned short vlds[64][40];

  int tid = threadIdx.x;
  int lane = tid & 63, w = tid >> 6;
  int ln = lane & 15, g = lane >> 4;
  int row0 = blockIdx.x * 32;

  int nc = w * 16 + ln;
  const unsigned short* wpq = Wt + (size_t)(0 * 64 + nc) * NC + g * 8;
  const unsigned short* wpk = Wt + (size_t)(1 * 64 + nc) * NC + g * 8;
  const unsigned short* wpv = Wt + (size_t)(2 * 64 + nc) * NC + g * 8;

  // staging: lane stages one 16B granule per instr; source pre-swizzled
  int scol = (((tid & 31) ^ ((tid >> 5) & 7)) << 2);      // float col in [0,128)
  const float* xst = x + (size_t)(row0 + (tid >> 5)) * NC + scol;  // + i*8 rows

  f32x4 acc[2][3];
#pragma unroll
  for (int rf = 0; rf < 2; ++rf)
#pragma unroll
    for (int j = 0; j < 3; ++j) acc[rf][j] = (f32x4){0.f, 0.f, 0.f, 0.f};

  // prologue: stage phase 0 into buf 0
#pragma unroll
  for (int i = 0; i < 4; ++i)
    stage16(xst + (size_t)i * 8 * NC, xs2[0] + i * 4096 + w * 1024, lane);
  __syncthreads();

#pragma unroll 1
  for (int p = 0; p < 8; ++p) {
    // stage phase p+1 into the other buffer (its old readers passed barrier)
    if (p < 7) {
#pragma unroll
      for (int i = 0; i < 4; ++i)
        stage16(xst + (size_t)i * 8 * NC + (p + 1) * 128,
                xs2[(p + 1) & 1] + i * 4096 + w * 1024, lane);
    }
    // compute phase p from buf[p&1]
    const char* bufc = xs2[p & 1];
#pragma unroll
    for (int c0 = 0; c0 < 128; c0 += 32) {
      bf16x8 a[2];
#pragma unroll
      for (int rf = 0; rf < 2; ++rf) {
        int row = rf * 16 + ln;
        int blk0 = (c0 >> 2) + g * 2;
        int by0 = row * 512 + ((blk0 ^ (ln & 7)) << 4);
        int by1 = row * 512 + (((blk0 + 1) ^ (ln & 7)) << 4);
        f32x4 lo = *(const f32x4*)(bufc + by0);
        f32x4 hi = *(const f32x4*)(bufc + by1);
#pragma unroll
        for (int j = 0; j < 4; ++j) {
          a[rf][j] = (short)f2bf(lo[j]);
          a[rf][4 + j] = (short)f2bf(hi[j]);
        }
      }
      int kg = p * 128 + c0;
      bf16x8 bq = *(const bf16x8*)(wpq + kg);
      bf16x8 bk = *(const bf16x8*)(wpk + kg);
      bf16x8 bv = *(const bf16x8*)(wpv + kg);
      acc[0][0] = mfma32(a[0], bq, acc[0][0]);
      acc[1][0] = mfma32(a[1], bq, acc[1][0]);
      acc[0][1] = mfma32(a[0], bk, acc[0][1]);
      acc[1][1] = mfma32(a[1], bk, acc[1][1]);
      acc[0][2] = mfma32(a[0], bv, acc[0][2]);
      acc[1][2] = mfma32(a[1], bv, acc[1][2]);
    }
    __syncthreads();   // drains staging vmcnt; buf[(p+1)&1] ready
  }

  // ---- epilogue: q,k direct; v via LDS transpose
#pragma unroll
  for (int rf = 0; rf < 2; ++rf)
#pragma unroll
    for (int r = 0; r < 4; ++r) {
      int row = row0 + rf * 16 + g * 4 + r;
      qo[(size_t)row * NH + nc] = f2bf(acc[rf][0][r]);
      ko[(size_t)row * NH + nc] = f2bf(acc[rf][1][r]);
      vlds[nc][rf * 16 + g * 4 + r] = f2bf(acc[rf][2][r]);
    }
  __syncthreads();
  {
    int b = row0 / NT, t0b = row0 % NT;
    int hh = tid >> 2, ts = (tid & 3) * 8;
    *(bf16x8*)(vo + (size_t)(b * NH + hh) * NT + t0b + ts) = *(const bf16x8*)&vlds[hh][ts];
  }
}

// ---------------------------------------------------------------------------
// Kernel 2: causal flash attention, v6. Swapped QK^T chains into PV's
// B-operand with zero shuffles. NEW: wave = 32 queries (two 16-q subtiles
// sharing every K/V load -> memory requests per query HALVED). Block = one
// balanced tile-pair (j, 63-j of 32 queries) processed sequentially ->
// constant work per block; 256 blocks x 256 thr = exactly 1 block/CU.
// b = bid&7 keeps each batch's K/V L2-resident on one XCD. 4-way key-split
// across waves, private state folded by wave 0, defer-rescale THR=8.
// ---------------------------------------------------------------------------
__global__ __launch_bounds__(256) void attn_kernel(const unsigned short* __restrict__ qw,
                                                   const unsigned short* __restrict__ kw,
                                                   const unsigned short* __restrict__ vw,
                                                   float* __restrict__ out) {
  __shared__ float mbuf[3][64][40];
  __shared__ float olds[32][68];

  int tid = threadIdx.x;
  int lane = tid & 63, ks = tid >> 6;
  int ln = lane & 15, g = lane >> 4;
  int bid = blockIdx.x;
  int b = bid & 7;
  int pr = bid >> 3;   // 0..31

  const unsigned short* kb = kw + (size_t)b * NT * NH + g * 8;
  const unsigned short* vb = vw + (size_t)b * NH * NT;

#pragma unroll 1
  for (int seg = 0; seg < 2; ++seg) {
    int tile = seg ? (63 - pr) : pr;
    int t0 = tile * 32;
    int tqA = t0 + ln, tqB = t0 + 16 + ln;

    const unsigned short* qpA = qw + (size_t)(b * NT + tqA) * NH + g * 8;
    const unsigned short* qpB = qw + (size_t)(b * NT + tqB) * NH + g * 8;
    bf16x8 qa0 = *(const bf16x8*)(qpA);
    bf16x8 qa1 = *(const bf16x8*)(qpA + 32);
    bf16x8 qb0 = *(const bf16x8*)(qpB);
    bf16x8 qb1 = *(const bf16x8*)(qpB + 32);

    f32x4 oaccA[4], oaccB[4];
#pragma unroll
    for (int i = 0; i < 4; ++i) {
      oaccA[i] = (f32x4){0.f, 0.f, 0.f, 0.f};
      oaccB[i] = (f32x4){0.f, 0.f, 0.f, 0.f};
    }
    float mA = -1e30f, lA = 0.f, mB = -1e30f, lB = 0.f;

    int send = t0 + 32;
    for (int s0 = ks * 64; s0 < send; s0 += 256) {
      // ---- S^T = K x Q^T for both q-subtiles (K regs shared)
      f32x4 sA[4], sB[4];
#pragma unroll
      for (int st = 0; st < 4; ++st) {
        const unsigned short* kp = kb + (size_t)(s0 + st * 16 + ln) * NH;
        bf16x8 k0 = *(const bf16x8*)(kp);
        bf16x8 k1 = *(const bf16x8*)(kp + 32);
        f32x4 a = (f32x4){0.f, 0.f, 0.f, 0.f};
        a = mfma32(k0, qa0, a);
        a = mfma32(k1, qa1, a);
        sA[st] = a;
        f32x4 c = (f32x4){0.f, 0.f, 0.f, 0.f};
        c = mfma32(k0, qb0, c);
        c = mfma32(k1, qb1, c);
        sB[st] = c;
      }
      // ---- causal masks (wave-uniform outer branches)
      if (s0 + 63 > t0) {
#pragma unroll
        for (int st = 0; st < 4; ++st)
#pragma unroll
          for (int r = 0; r < 4; ++r)
            if (s0 + st * 16 + g * 4 + r > tqA) sA[st][r] = -1e30f;
      }
      if (s0 + 63 > t0 + 16) {
#pragma unroll
        for (int st = 0; st < 4; ++st)
#pragma unroll
          for (int r = 0; r < 4; ++r)
            if (s0 + st * 16 + g * 4 + r > tqB) sB[st][r] = -1e30f;
      }
      // ---- online softmax A (base-2, deferred rescale)
      float tmax = -1e30f;
#pragma unroll
      for (int st = 0; st < 4; ++st)
#pragma unroll
        for (int r = 0; r < 4; ++r) tmax = fmaxf(tmax, sA[st][r]);
      tmax = fmaxf(tmax, __shfl_xor(tmax, 16));
      tmax = fmaxf(tmax, __shfl_xor(tmax, 32));
      if (__any(tmax > mA + 8.f)) {
        float mnew = fmaxf(mA, tmax);
        float sfac = exp2f(mA - mnew);
        lA *= sfac;
#pragma unroll
        for (int hf = 0; hf < 4; ++hf)
#pragma unroll
          for (int r = 0; r < 4; ++r) oaccA[hf][r] *= sfac;
        mA = mnew;
      }
      float psum = 0.f;
      bf16x4 pA[4];
#pragma unroll
      for (int st = 0; st < 4; ++st)
#pragma unroll
        for (int r = 0; r < 4; ++r) {
          float p = exp2f(sA[st][r] - mA);
          psum += p;
          pA[st][r] = (short)f2bf(p);
        }
      psum += __shfl_xor(psum, 16);
      psum += __shfl_xor(psum, 32);
      lA += psum;
      // ---- online softmax B
      tmax = -1e30f;
#pragma unroll
      for (int st = 0; st < 4; ++st)
#pragma unroll
        for (int r = 0; r < 4; ++r) tmax = fmaxf(tmax, sB[st][r]);
      tmax = fmaxf(tmax, __shfl_xor(tmax, 16));
      tmax = fmaxf(tmax, __shfl_xor(tmax, 32));
      if (__any(tmax > mB + 8.f)) {
        float mnew = fmaxf(mB, tmax);
        float sfac = exp2f(mB - mnew);
        lB *= sfac;
#pragma unroll
        for (int hf = 0; hf < 4; ++hf)
#pragma unroll
          for (int r = 0; r < 4; ++r) oaccB[hf][r] *= sfac;
        mB = mnew;
      }
      psum = 0.f;
      bf16x4 pB[4];
#pragma unroll
      for (int st = 0; st < 4; ++st)
#pragma unroll
        for (int r = 0; r < 4; ++r) {
          float p = exp2f(sB[st][r] - mB);
          psum += p;
          pB[st][r] = (short)f2bf(p);
        }
      psum += __shfl_xor(psum, 16);
      psum += __shfl_xor(psum, 32);
      lB += psum;

      // ---- PV: V loads shared by both q-subtiles
#pragma unroll
      for (int hf = 0; hf < 4; ++hf) {
        const unsigned short* vp = vb + (size_t)(hf * 16 + ln) * NT + s0 + g * 4;
#pragma unroll
        for (int st = 0; st < 4; ++st) {
          bf16x4 va = *(const bf16x4*)(vp + st * 16);
          oaccA[hf] = mfma16(va, pA[st], oaccA[hf]);
          oaccB[hf] = mfma16(va, pB[st], oaccB[hf]);
        }
      }
    }

    // ---- fold the 4 key-split partials (wave 0 accumulates)
    if (ks) {
      float* d = mbuf[ks - 1][lane];
      d[0] = mA; d[1] = lA;
      d[18] = mB; d[19] = lB;
#pragma unroll
      for (int hf = 0; hf < 4; ++hf)
#pragma unroll
        for (int r = 0; r < 4; ++r) {
          d[2 + hf * 4 + r] = oaccA[hf][r];
          d[20 + hf * 4 + r] = oaccB[hf][r];
        }
    }
    __syncthreads();
    if (ks == 0) {
#pragma unroll
      for (int j = 0; j < 3; ++j) {
        const float* d = mbuf[j][lane];
        float mo = d[0], lo = d[1];
        float mx = fmaxf(mA, mo);
        float fS = exp2f(mA - mx), fO = exp2f(mo - mx);
        lA = lA * fS + lo * fO;
#pragma unroll
        for (int hf = 0; hf < 4; ++hf)
#pragma unroll
          for (int r = 0; r < 4; ++r)
            oaccA[hf][r] = oaccA[hf][r] * fS + d[2 + hf * 4 + r] * fO;
        mA = mx;
        mo = d[18]; lo = d[19];
        mx = fmaxf(mB, mo);
        fS = exp2f(mB - mx); fO = exp2f(mo - mx);
        lB = lB * fS + lo * fO;
#pragma unroll
        for (int hf = 0; hf < 4; ++hf)
#pragma unroll
          for (int r = 0; r < 4; ++r)
            oaccB[hf][r] = oaccB[hf][r] * fS + d[20 + hf * 4 + r] * fO;
        mB = mx;
      }
      float invA = 1.f / lA, invB = 1.f / lB;
#pragma unroll
      for (int hf = 0; hf < 4; ++hf)
#pragma unroll
        for (int r = 0; r < 4; ++r) {
          olds[ln][hf * 16 + g * 4 + r] = oaccA[hf][r] * invA;
          olds[16 + ln][hf * 16 + g * 4 + r] = oaccB[hf][r] * invB;
        }
    }
    __syncthreads();
    // ---- transposed store out[b][t][h]
    if (tid < 128) {
      int tl = tid >> 2, h0 = (tid & 3) * 16;
      size_t obase = (size_t)(b * NT + t0 + tl) * NH + h0;
#pragma unroll
      for (int vv = 0; vv < 4; ++vv) {
        float4 t4 = make_float4(olds[tl][h0 + vv * 4 + 0], olds[tl][h0 + vv * 4 + 1],
                                olds[tl][h0 + vv * 4 + 2], olds[tl][h0 + vv * 4 + 3]);
        *(float4*)(out + obase + vv * 4) = t4;
      }
    }
    __syncthreads();   // protect mbuf/olds before next segment
  }
}

// ---------------------------------------------------------------------------
extern "C" void kernel_launch(void* const* d_in, const int* in_sizes, int n_in,
                              void* d_out, int out_size, void* d_ws, size_t ws_size,
                              hipStream_t stream) {
  const float* x  = (const float*)d_in[0];
  const float* Wq = (const float*)d_in[1];
  const float* Wk = (const float*)d_in[2];
  const float* Wv = (const float*)d_in[3];
  float* out = (float*)d_out;

  unsigned short* Wt = (unsigned short*)d_ws;
  unsigned short* q  = (unsigned short*)((char*)d_ws + (1 << 19));
  unsigned short* k  = q + (size_t)NB * NT * NH;
  unsigned short* v  = k + (size_t)NB * NT * NH;

  wt_kernel<<<48, 256, 0, stream>>>(Wq, Wk, Wv, Wt);
  proj_kernel<<<(NB * NT) / 32, 256, 0, stream>>>(x, Wt, q, k, v);
  attn_kernel<<<256, 256, 0, stream>>>(q, k, v, out);
}